// Round 14
// baseline (328.444 us; speedup 1.0000x reference)
//
#include <hip/hip_runtime.h>
#include <hip/hip_fp16.h>

// GraphEmbedding2: 3-layer GCN (DGL GraphConv, norm='both') + per-graph mean pooling.
// N=50000 nodes, E=600000 edges, d=128, G=64 graphs.
// fp16 gather operands (R6); LDS-histogram degrees + LDS-cursor CSR fill (R5/R8,
// zero global atomics); MFMA GEMM fp16-in/fp32-acc (R9); 8-deep clamped gather MLP (R10).
// R13: HIST_S 64->32 (halves partial/cursor traffic), scan_top folded into
// scan_write (each block redundantly scans the 196 block sums in LDS).
// Reverted-for-cause: R7 fusion (occupancy+LDS conflicts), R11 range passes
// (no FETCH drop, serialized MLP).

#define DIM 128
#define GRAPHS 64

typedef _Float16 half8 __attribute__((ext_vector_type(8)));
typedef float floatx4 __attribute__((ext_vector_type(4)));

// ---------------------------------------------------------------- degree histogram (LDS)
#define HIST_R 4
#define HIST_S 32
#define NPR 12500          // nodes per range (HIST_R * NPR = 50000)
#define LDSW (NPR / 2)     // 6250 u32 words, 25 KB LDS

__global__ __launch_bounds__(256) void k_hist(const int* __restrict__ src,
                                              const int* __restrict__ dst,
                                              unsigned* __restrict__ partial, int E) {
    __shared__ unsigned hist[LDSW];
    int b = blockIdx.x;
    int a = b / (HIST_R * HIST_S);       // 0: src, 1: dst
    int r = (b / HIST_S) % HIST_R;       // node range
    int s = b % HIST_S;                  // edge slice
    const int* arr = a ? dst : src;
    for (int i = threadIdx.x; i < LDSW; i += 256) hist[i] = 0;
    __syncthreads();
    int chunk = (E + HIST_S - 1) / HIST_S;
    int e0 = s * chunk;
    int e1 = min(e0 + chunk, E);
    unsigned base = (unsigned)(r * NPR);
    for (int i = e0 + threadIdx.x; i < e1; i += 256) {
        unsigned n = (unsigned)arr[i] - base;
        if (n < NPR) atomicAdd(&hist[n >> 1], 1u << ((n & 1) * 16));
    }
    __syncthreads();
    unsigned* outp = partial + ((size_t)(a * HIST_R + r) * HIST_S + s) * LDSW;
    for (int i = threadIdx.x; i < LDSW; i += 256) outp[i] = hist[i];
}

// ---------------------------------------------------------------- merge + block sums
// Blocks [0, nb): dst — nd, inc, per-256-node bsum. Blocks [nb, 2nb): src — ns.
__global__ __launch_bounds__(256) void k_hist_merge(const unsigned* __restrict__ partial,
                                                    float* __restrict__ ns,
                                                    float* __restrict__ nd,
                                                    int* __restrict__ inc,
                                                    int* __restrict__ bsum, int N) {
    __shared__ int sred[256];
    int nb = (N + 255) / 256;
    int isDst = (blockIdx.x < nb) ? 1 : 0;
    int cb = isDst ? blockIdx.x : blockIdx.x - nb;
    int n = cb * 256 + threadIdx.x;
    int deg = 0;
    if (n < N) {
        int a = isDst ? 1 : 0;
        int r = n / NPR;
        int w = (n % NPR) >> 1;
        int field = (n & 1) * 16;
        const unsigned* p = partial + ((size_t)(a * HIST_R + r) * HIST_S) * LDSW + w;
        unsigned sum = 0;
#pragma unroll
        for (int s = 0; s < HIST_S; ++s) sum += p[(size_t)s * LDSW];
        deg = (int)((sum >> field) & 0xFFFFu);
        float nrm = rsqrtf(fmaxf((float)deg, 1.0f));
        if (isDst) { nd[n] = nrm; inc[n] = deg; }
        else       { ns[n] = nrm; }
    }
    if (isDst) {
        sred[threadIdx.x] = deg;
        __syncthreads();
        for (int off = 128; off > 0; off >>= 1) {
            if (threadIdx.x < off) sred[threadIdx.x] += sred[threadIdx.x + off];
            __syncthreads();
        }
        if (threadIdx.x == 0) bsum[cb] = sred[0];
    }
}

// ---------------------------------------------------------------- scan_write + cursor
// Phase 0: every block scans the nb (<256) raw block sums in LDS -> its global base
// (scan_top folded in). Phase A: block-local scan of inc -> row_ptr. Phase B:
// threads 0..127 write per-(range,slice) cursors from the dst histogram prefix.
// Block 0 zero-inits gsum/gcnt.
__global__ __launch_bounds__(256) void k_scan_write(const int* __restrict__ inc,
                                                    const int* __restrict__ bsum,
                                                    const unsigned* __restrict__ partial,
                                                    int* __restrict__ row_ptr,
                                                    int* __restrict__ cur,
                                                    float* __restrict__ gsum,
                                                    int* __restrict__ gcnt, int N) {
    __shared__ int sb[256];
    __shared__ int s[256];
    __shared__ int exs[256];
    int nb = (N + 255) / 256;
    int t = threadIdx.x;

    // phase 0: exclusive-scan block sums
    int bv = (t < nb) ? bsum[t] : 0;
    sb[t] = bv;
    __syncthreads();
    for (int off = 1; off < 256; off <<= 1) {
        int u = (t >= off) ? sb[t - off] : 0;
        __syncthreads();
        sb[t] += u;
        __syncthreads();
    }
    int excl = sb[t] - bv;
    __syncthreads();
    sb[t] = excl;
    __syncthreads();
    int blockBase = sb[blockIdx.x];

    // phase A: local scan of inc
    int B = blockIdx.x * 256;
    int i = B + t;
    int v = (i < N) ? inc[i] : 0;
    s[t] = v;
    __syncthreads();
    for (int off = 1; off < 256; off <<= 1) {
        int u = (t >= off) ? s[t - off] : 0;
        __syncthreads();
        s[t] += u;
        __syncthreads();
    }
    int ex = blockBase + s[t] - v;  // global exclusive prefix
    exs[t] = ex;
    if (i < N) row_ptr[i] = ex;
    if (i == N - 1) row_ptr[N] = ex + v;
    if (blockIdx.x == 0) {
        for (int j = t; j < GRAPHS * DIM; j += 256) gsum[j] = 0.0f;
        if (t < GRAPHS) gcnt[t] = 0;
    }
    __syncthreads();

    // phase B: per-slice cursors
    if (t < 128) {
        int n0 = B + 2 * t;
        if (n0 < N) {
            int r = n0 / NPR;
            int w = (n0 % NPR) >> 1;
            const unsigned* p = partial + ((size_t)(HIST_R + r) * HIST_S) * LDSW + w;
            int run0 = exs[2 * t];
            int run1 = exs[2 * t + 1];
            int* c = cur + (size_t)r * HIST_S * NPR + 2 * w;
#pragma unroll
            for (int sl = 0; sl < HIST_S; ++sl) {
                c[(size_t)sl * NPR + 0] = run0;
                c[(size_t)sl * NPR + 1] = run1;
                unsigned hv = p[(size_t)sl * LDSW];
                run0 += (int)(hv & 0xFFFFu);
                run1 += (int)(hv >> 16);
            }
        }
    }
}

// ---------------------------------------------------------------- CSR fill (LDS cursors)
__global__ __launch_bounds__(256) void k_fill2(const int* __restrict__ src,
                                               const int* __restrict__ dst,
                                               const int* __restrict__ cur,
                                               int* __restrict__ csr, int E) {
    __shared__ int lcur[NPR];   // 50 KB
    int r = blockIdx.x / HIST_S;
    int s = blockIdx.x % HIST_S;
    const int* cs = cur + (size_t)(r * HIST_S + s) * NPR;
    for (int i = threadIdx.x; i < NPR; i += 256) lcur[i] = cs[i];
    __syncthreads();
    int chunk = (E + HIST_S - 1) / HIST_S;
    int e0 = s * chunk;
    int e1 = min(e0 + chunk, E);
    unsigned base = (unsigned)(r * NPR);
    for (int i = e0 + threadIdx.x; i < e1; i += 256) {
        unsigned d = (unsigned)dst[i] - base;
        if (d < NPR) {
            int p = atomicAdd(&lcur[d], 1);   // LDS atomic
            csr[p] = src[i];
        }
    }
}

// ---------------------------------------------------------------- prep: h->fp16(h*ns), W1..3->fp16^T
__global__ void k_prep(const float4* __restrict__ h, const float* __restrict__ ns,
                       uint2* __restrict__ A,
                       const float* __restrict__ W1, const float* __restrict__ W2,
                       const float* __restrict__ W3, _Float16* __restrict__ Wt1,
                       _Float16* __restrict__ Wt2, _Float16* __restrict__ Wt3, int N) {
    int i = blockIdx.x * blockDim.x + threadIdx.x;
    int nf4 = N * 32;
    if (i < nf4) {
        int n = i >> 5;
        float s = ns[n];
        float4 v = h[i];
        __half2 p0 = __floats2half2_rn(v.x * s, v.y * s);
        __half2 p1 = __floats2half2_rn(v.z * s, v.w * s);
        uint2 o;
        o.x = *(unsigned*)&p0;
        o.y = *(unsigned*)&p1;
        A[i] = o;
    } else {
        int j = i - nf4;               // 0 .. 3*16384-1
        if (j < 3 * 16384) {
            int which = j >> 14;
            int local = j & 16383;
            int k = local >> 7;
            int n = local & 127;
            const float* W = (which == 0) ? W1 : (which == 1) ? W2 : W3;
            _Float16* Wt = (which == 0) ? Wt1 : (which == 1) ? Wt2 : Wt3;
            Wt[(size_t)n * DIM + k] = (_Float16)W[local];
        }
    }
}

// ---------------------------------------------------------------- aggregation (R10 form)
// One wave per node, paired edges (lanes 0-31: even, 32-63: odd). Single clamped
// 16-edge round: 8 gathers in flight per lane, indices clamped to e1-1 (legal),
// accumulation predicated on e < e1. No branch between index load and gather.
__global__ __launch_bounds__(256) void k_agg(const uint2* __restrict__ A,
                                             const int* __restrict__ row_ptr,
                                             const int* __restrict__ csr,
                                             const float* __restrict__ nd,
                                             uint2* __restrict__ Bh, int N) {
    int gtid = blockIdx.x * blockDim.x + threadIdx.x;
    int node = gtid >> 6;
    int lane = threadIdx.x & 63;
    if (node >= N) return;
    int e0 = row_ptr[node];
    int e1 = row_ptr[node + 1];
    int half = lane >> 5;    // 0: even edge, 1: odd edge
    int l8 = lane & 31;      // 8-byte slot within 256B row
    float ax = 0.f, ay = 0.f, az = 0.f, aw = 0.f;

    for (int base = e0; base < e1; base += 16) {
        int idx[8];
        uint2 u[8];
#pragma unroll
        for (int j = 0; j < 8; ++j) {
            int ee = base + 2 * j + half;
            idx[j] = csr[min(ee, e1 - 1)];
        }
#pragma unroll
        for (int j = 0; j < 8; ++j) {
            u[j] = A[(size_t)idx[j] * 32 + l8];
        }
#pragma unroll
        for (int j = 0; j < 8; ++j) {
            int ee = base + 2 * j + half;
            if (ee < e1) {
                __half2 p0 = *(__half2*)&u[j].x;
                __half2 p1 = *(__half2*)&u[j].y;
                float2 f0 = __half22float2(p0);
                float2 f1 = __half22float2(p1);
                ax += f0.x; ay += f0.y; az += f1.x; aw += f1.y;
            }
        }
    }

    ax += __shfl_xor(ax, 32);
    ay += __shfl_xor(ay, 32);
    az += __shfl_xor(az, 32);
    aw += __shfl_xor(aw, 32);

    if (half == 0) {
        float scale = nd[node];
        __half2 p0 = __floats2half2_rn(ax * scale, ay * scale);
        __half2 p1 = __floats2half2_rn(az * scale, aw * scale);
        uint2 o;
        o.x = *(unsigned*)&p0;
        o.y = *(unsigned*)&p1;
        Bh[(size_t)node * 32 + l8] = o;
    }
}

// ---------------------------------------------------------------- GEMM on matrix cores
// X = relu(Bin @ W + b). Bin fp16 [N][128], Wt fp16 [n][k]. 4 waves x 16 rows = 64 rows/block.
// A: lane=A[m=l16][k=quad*8+j]; B: lane=B[k=quad*8+j][n=l16]; C/D: col=l16, row=quad*4+reg.
// Output fp16; SCALE_NS multiplies rows by ns (layers 1-2).
template <bool SCALE_NS>
__global__ __launch_bounds__(256) void k_gemm_mfma(
    const _Float16* __restrict__ Bin, const _Float16* __restrict__ Wt,
    const float* __restrict__ bias, const float* __restrict__ ns,
    _Float16* __restrict__ Xout, int N) {
    int tid = threadIdx.x;
    int wave = tid >> 6;
    int lane = tid & 63;
    int quad = lane >> 4;
    int l16 = lane & 15;
    int r0 = blockIdx.x * 64 + wave * 16;
    int arow = r0 + l16;

    half8 a[4];
#pragma unroll
    for (int q = 0; q < 4; ++q) {
        if (arow < N) {
            a[q] = *(const half8*)&Bin[(size_t)arow * DIM + q * 32 + quad * 8];
        } else {
            a[q] = half8{0, 0, 0, 0, 0, 0, 0, 0};
        }
    }

    floatx4 acc[8];
#pragma unroll
    for (int c = 0; c < 8; ++c) acc[c] = floatx4{0.f, 0.f, 0.f, 0.f};

#pragma unroll
    for (int c = 0; c < 8; ++c) {
#pragma unroll
        for (int q = 0; q < 4; ++q) {
            half8 b = *(const half8*)&Wt[(size_t)(c * 16 + l16) * DIM + q * 32 + quad * 8];
            acc[c] = __builtin_amdgcn_mfma_f32_16x16x32_f16(a[q], b, acc[c], 0, 0, 0);
        }
    }

    float bb[8];
#pragma unroll
    for (int c = 0; c < 8; ++c) bb[c] = bias[c * 16 + l16];

#pragma unroll
    for (int r = 0; r < 4; ++r) {
        int row = r0 + quad * 4 + r;
        if (row >= N) continue;
        float sr = SCALE_NS ? ns[row] : 1.0f;
#pragma unroll
        for (int c = 0; c < 8; ++c) {
            float v = fmaxf(acc[c][r] + bb[c], 0.0f);
            Xout[(size_t)row * DIM + c * 16 + l16] = (_Float16)(v * sr);
        }
    }
}

// ---------------------------------------------------------------- pooling (fp16 input)
#define POOL_NODES 32
__global__ void k_pool_partial(const _Float16* __restrict__ X, const int* __restrict__ gid,
                               float* __restrict__ gsum, int* __restrict__ gcnt, int N) {
    int n0 = blockIdx.x * POOL_NODES;
    int d = threadIdx.x;  // 0..127
    int nend = min(n0 + POOL_NODES, N);
    float run = 0.0f;
    int cnt = 0;
    int curg = -1;
    for (int n = n0; n < nend; ++n) {
        int g = gid[n];
        if (g != curg) {
            if (cnt > 0) {
                atomicAdd(&gsum[curg * DIM + d], run);
                if (d == 0) atomicAdd(&gcnt[curg], cnt);
            }
            run = 0.0f; cnt = 0; curg = g;
        }
        run += (float)X[(size_t)n * DIM + d];
        cnt++;
    }
    if (cnt > 0) {
        atomicAdd(&gsum[curg * DIM + d], run);
        if (d == 0) atomicAdd(&gcnt[curg], cnt);
    }
}

__global__ void k_finalize(const float* __restrict__ gsum, const int* __restrict__ gcnt,
                           float* __restrict__ out, int G) {
    int i = blockIdx.x * blockDim.x + threadIdx.x;
    if (i < G * DIM) {
        int g = i >> 7;
        float c = fmaxf((float)gcnt[g], 1.0f);
        out[i] = gsum[i] / c;
    }
}

// ---------------------------------------------------------------- launch
extern "C" void kernel_launch(void* const* d_in, const int* in_sizes, int n_in,
                              void* d_out, int out_size, void* d_ws, size_t ws_size,
                              hipStream_t stream) {
    const float* h   = (const float*)d_in[0];
    const int*   src = (const int*)d_in[1];
    const int*   dst = (const int*)d_in[2];
    const int*   gid = (const int*)d_in[3];
    const float* W1  = (const float*)d_in[4];
    const float* b1  = (const float*)d_in[5];
    const float* W2  = (const float*)d_in[6];
    const float* b2  = (const float*)d_in[7];
    const float* W3  = (const float*)d_in[8];
    const float* b3  = (const float*)d_in[9];

    const int N = in_sizes[0] / DIM;   // 50000
    const int E = in_sizes[1];         // 600000
    const int G = GRAPHS;
    float* out = (float*)d_out;

    char* ws = (char*)d_ws;
    size_t off = 0;
    auto alloc = [&](size_t bytes) -> void* {
        void* p = ws + off;
        off += (bytes + 255) & ~(size_t)255;
        return p;
    };
    const int nb = (N + 255) / 256;    // 196
    uint2* Ah0     = (uint2*)alloc((size_t)N * DIM * 2);  // fp16 gather operand (ping)
    uint2* Ah1     = (uint2*)alloc((size_t)N * DIM * 2);  // fp16 pong
    uint2* Bh      = (uint2*)alloc((size_t)N * DIM * 2);  // agg output (fp16)
    _Float16* X3   = (_Float16*)alloc((size_t)N * DIM * 2);  // layer-3 fp16 output
    _Float16* Wt1  = (_Float16*)alloc((size_t)DIM * DIM * 2);
    _Float16* Wt2  = (_Float16*)alloc((size_t)DIM * DIM * 2);
    _Float16* Wt3  = (_Float16*)alloc((size_t)DIM * DIM * 2);
    float* ns      = (float*)alloc((size_t)N * 4);
    float* nd      = (float*)alloc((size_t)N * 4);
    int*   inc     = (int*)alloc((size_t)N * 4);
    unsigned* partial = (unsigned*)alloc((size_t)2 * HIST_R * HIST_S * LDSW * 4);  // 6.4 MB
    int*   cur     = (int*)alloc((size_t)HIST_R * HIST_S * NPR * 4);               // 6.4 MB
    int*   row_ptr = (int*)alloc((size_t)(N + 1) * 4);
    int*   csr     = (int*)alloc((size_t)E * 4);
    float* gsum    = (float*)alloc((size_t)G * DIM * 4);
    int*   gcnt    = (int*)alloc((size_t)G * 4);
    int*   bsum    = (int*)alloc((size_t)nb * 4);

    // degrees via LDS histograms (no global atomics)
    k_hist<<<2 * HIST_R * HIST_S, 256, 0, stream>>>(src, dst, partial, E);
    // merge -> ns/nd/inc + per-block sums
    k_hist_merge<<<2 * nb, 256, 0, stream>>>(partial, ns, nd, inc, bsum, N);
    // row_ptr + per-(range,slice) cursors + gsum/gcnt zero (scan_top + cursor folded in)
    k_scan_write<<<nb, 256, 0, stream>>>(inc, bsum, partial, row_ptr, cur, gsum, gcnt, N);
    k_fill2<<<HIST_R * HIST_S, 256, 0, stream>>>(src, dst, cur, csr, E);

    // Ah0 = fp16(h*ns) + weights -> fp16 transposed (single launch)
    int prepThreads = N * 32 + 3 * 16384;
    k_prep<<<(prepThreads + 255) / 256, 256, 0, stream>>>((const float4*)h, ns, Ah0,
                                                          W1, W2, W3, Wt1, Wt2, Wt3, N);

    int aggBlocks  = (N * 64 + 255) / 256;
    int gemmBlocks = (N + 63) / 64;

    // layer 1
    k_agg<<<aggBlocks, 256, 0, stream>>>(Ah0, row_ptr, csr, nd, Bh, N);
    k_gemm_mfma<true><<<gemmBlocks, 256, 0, stream>>>((const _Float16*)Bh, Wt1, b1, ns, (_Float16*)Ah1, N);
    // layer 2
    k_agg<<<aggBlocks, 256, 0, stream>>>(Ah1, row_ptr, csr, nd, Bh, N);
    k_gemm_mfma<true><<<gemmBlocks, 256, 0, stream>>>((const _Float16*)Bh, Wt2, b2, ns, (_Float16*)Ah0, N);
    // layer 3 (fp16 out, no ns)
    k_agg<<<aggBlocks, 256, 0, stream>>>(Ah0, row_ptr, csr, nd, Bh, N);
    k_gemm_mfma<false><<<gemmBlocks, 256, 0, stream>>>((const _Float16*)Bh, Wt3, b3, ns, X3, N);

    k_pool_partial<<<(N + POOL_NODES - 1) / POOL_NODES, 128, 0, stream>>>(X3, gid, gsum, gcnt, N);
    k_finalize<<<(G * DIM + 255) / 256, 256, 0, stream>>>(gsum, gcnt, out, G);
}

// Round 15
// 306.702 us; speedup vs baseline: 1.0709x; 1.0709x over previous
//
#include <hip/hip_runtime.h>
#include <hip/hip_fp16.h>

// GraphEmbedding2: 3-layer GCN (DGL GraphConv, norm='both') + per-graph mean pooling.
// N=50000 nodes, E=600000 edges, d=128, G=64 graphs.
// fp16 gather operands (R6); LDS-histogram degrees + LDS-cursor CSR fill (R5/R8,
// zero global atomics); MFMA GEMM fp16-in/fp32-acc (R9); 8-deep clamped gather MLP (R10);
// scan_top folded into scan_write (R13).
// R14: HIST_S restored to 64 — R13's HIST_S=32 halved k_fill2's grid to 128 blocks
// (occupancy 4.7%, 43µs): fill2 is launch-parallelism-bound, not byte-bound.
// Reverted-for-cause: R7 fusion (occupancy+LDS conflicts), R11 range passes
// (no FETCH drop, serialized MLP), R13 HIST_S=32 (grid coverage).

#define DIM 128
#define GRAPHS 64

typedef _Float16 half8 __attribute__((ext_vector_type(8)));
typedef float floatx4 __attribute__((ext_vector_type(4)));

// ---------------------------------------------------------------- degree histogram (LDS)
#define HIST_R 4
#define HIST_S 64
#define NPR 12500          // nodes per range (HIST_R * NPR = 50000)
#define LDSW (NPR / 2)     // 6250 u32 words, 25 KB LDS

__global__ __launch_bounds__(256) void k_hist(const int* __restrict__ src,
                                              const int* __restrict__ dst,
                                              unsigned* __restrict__ partial, int E) {
    __shared__ unsigned hist[LDSW];
    int b = blockIdx.x;
    int a = b / (HIST_R * HIST_S);       // 0: src, 1: dst
    int r = (b / HIST_S) % HIST_R;       // node range
    int s = b % HIST_S;                  // edge slice
    const int* arr = a ? dst : src;
    for (int i = threadIdx.x; i < LDSW; i += 256) hist[i] = 0;
    __syncthreads();
    int chunk = (E + HIST_S - 1) / HIST_S;
    int e0 = s * chunk;
    int e1 = min(e0 + chunk, E);
    unsigned base = (unsigned)(r * NPR);
    for (int i = e0 + threadIdx.x; i < e1; i += 256) {
        unsigned n = (unsigned)arr[i] - base;
        if (n < NPR) atomicAdd(&hist[n >> 1], 1u << ((n & 1) * 16));
    }
    __syncthreads();
    unsigned* outp = partial + ((size_t)(a * HIST_R + r) * HIST_S + s) * LDSW;
    for (int i = threadIdx.x; i < LDSW; i += 256) outp[i] = hist[i];
}

// ---------------------------------------------------------------- merge + block sums
// Blocks [0, nb): dst — nd, inc, per-256-node bsum. Blocks [nb, 2nb): src — ns.
__global__ __launch_bounds__(256) void k_hist_merge(const unsigned* __restrict__ partial,
                                                    float* __restrict__ ns,
                                                    float* __restrict__ nd,
                                                    int* __restrict__ inc,
                                                    int* __restrict__ bsum, int N) {
    __shared__ int sred[256];
    int nb = (N + 255) / 256;
    int isDst = (blockIdx.x < nb) ? 1 : 0;
    int cb = isDst ? blockIdx.x : blockIdx.x - nb;
    int n = cb * 256 + threadIdx.x;
    int deg = 0;
    if (n < N) {
        int a = isDst ? 1 : 0;
        int r = n / NPR;
        int w = (n % NPR) >> 1;
        int field = (n & 1) * 16;
        const unsigned* p = partial + ((size_t)(a * HIST_R + r) * HIST_S) * LDSW + w;
        unsigned sum = 0;
#pragma unroll
        for (int s = 0; s < HIST_S; ++s) sum += p[(size_t)s * LDSW];
        deg = (int)((sum >> field) & 0xFFFFu);
        float nrm = rsqrtf(fmaxf((float)deg, 1.0f));
        if (isDst) { nd[n] = nrm; inc[n] = deg; }
        else       { ns[n] = nrm; }
    }
    if (isDst) {
        sred[threadIdx.x] = deg;
        __syncthreads();
        for (int off = 128; off > 0; off >>= 1) {
            if (threadIdx.x < off) sred[threadIdx.x] += sred[threadIdx.x + off];
            __syncthreads();
        }
        if (threadIdx.x == 0) bsum[cb] = sred[0];
    }
}

// ---------------------------------------------------------------- scan_write + cursor
// Phase 0: every block scans the nb (<256) raw block sums in LDS -> its global base.
// Phase A: block-local scan of inc -> row_ptr. Phase B: threads 0..127 write
// per-(range,slice) cursors from the dst histogram prefix. Block 0 zeroes gsum/gcnt.
__global__ __launch_bounds__(256) void k_scan_write(const int* __restrict__ inc,
                                                    const int* __restrict__ bsum,
                                                    const unsigned* __restrict__ partial,
                                                    int* __restrict__ row_ptr,
                                                    int* __restrict__ cur,
                                                    float* __restrict__ gsum,
                                                    int* __restrict__ gcnt, int N) {
    __shared__ int sb[256];
    __shared__ int s[256];
    __shared__ int exs[256];
    int nb = (N + 255) / 256;
    int t = threadIdx.x;

    // phase 0: exclusive-scan block sums
    int bv = (t < nb) ? bsum[t] : 0;
    sb[t] = bv;
    __syncthreads();
    for (int off = 1; off < 256; off <<= 1) {
        int u = (t >= off) ? sb[t - off] : 0;
        __syncthreads();
        sb[t] += u;
        __syncthreads();
    }
    int excl = sb[t] - bv;
    __syncthreads();
    sb[t] = excl;
    __syncthreads();
    int blockBase = sb[blockIdx.x];

    // phase A: local scan of inc
    int B = blockIdx.x * 256;
    int i = B + t;
    int v = (i < N) ? inc[i] : 0;
    s[t] = v;
    __syncthreads();
    for (int off = 1; off < 256; off <<= 1) {
        int u = (t >= off) ? s[t - off] : 0;
        __syncthreads();
        s[t] += u;
        __syncthreads();
    }
    int ex = blockBase + s[t] - v;  // global exclusive prefix
    exs[t] = ex;
    if (i < N) row_ptr[i] = ex;
    if (i == N - 1) row_ptr[N] = ex + v;
    if (blockIdx.x == 0) {
        for (int j = t; j < GRAPHS * DIM; j += 256) gsum[j] = 0.0f;
        if (t < GRAPHS) gcnt[t] = 0;
    }
    __syncthreads();

    // phase B: per-slice cursors
    if (t < 128) {
        int n0 = B + 2 * t;
        if (n0 < N) {
            int r = n0 / NPR;
            int w = (n0 % NPR) >> 1;
            const unsigned* p = partial + ((size_t)(HIST_R + r) * HIST_S) * LDSW + w;
            int run0 = exs[2 * t];
            int run1 = exs[2 * t + 1];
            int* c = cur + (size_t)r * HIST_S * NPR + 2 * w;
#pragma unroll
            for (int sl = 0; sl < HIST_S; ++sl) {
                c[(size_t)sl * NPR + 0] = run0;
                c[(size_t)sl * NPR + 1] = run1;
                unsigned hv = p[(size_t)sl * LDSW];
                run0 += (int)(hv & 0xFFFFu);
                run1 += (int)(hv >> 16);
            }
        }
    }
}

// ---------------------------------------------------------------- CSR fill (LDS cursors)
__global__ __launch_bounds__(256) void k_fill2(const int* __restrict__ src,
                                               const int* __restrict__ dst,
                                               const int* __restrict__ cur,
                                               int* __restrict__ csr, int E) {
    __shared__ int lcur[NPR];   // 50 KB
    int r = blockIdx.x / HIST_S;
    int s = blockIdx.x % HIST_S;
    const int* cs = cur + (size_t)(r * HIST_S + s) * NPR;
    for (int i = threadIdx.x; i < NPR; i += 256) lcur[i] = cs[i];
    __syncthreads();
    int chunk = (E + HIST_S - 1) / HIST_S;
    int e0 = s * chunk;
    int e1 = min(e0 + chunk, E);
    unsigned base = (unsigned)(r * NPR);
    for (int i = e0 + threadIdx.x; i < e1; i += 256) {
        unsigned d = (unsigned)dst[i] - base;
        if (d < NPR) {
            int p = atomicAdd(&lcur[d], 1);   // LDS atomic
            csr[p] = src[i];
        }
    }
}

// ---------------------------------------------------------------- prep: h->fp16(h*ns), W1..3->fp16^T
__global__ void k_prep(const float4* __restrict__ h, const float* __restrict__ ns,
                       uint2* __restrict__ A,
                       const float* __restrict__ W1, const float* __restrict__ W2,
                       const float* __restrict__ W3, _Float16* __restrict__ Wt1,
                       _Float16* __restrict__ Wt2, _Float16* __restrict__ Wt3, int N) {
    int i = blockIdx.x * blockDim.x + threadIdx.x;
    int nf4 = N * 32;
    if (i < nf4) {
        int n = i >> 5;
        float s = ns[n];
        float4 v = h[i];
        __half2 p0 = __floats2half2_rn(v.x * s, v.y * s);
        __half2 p1 = __floats2half2_rn(v.z * s, v.w * s);
        uint2 o;
        o.x = *(unsigned*)&p0;
        o.y = *(unsigned*)&p1;
        A[i] = o;
    } else {
        int j = i - nf4;               // 0 .. 3*16384-1
        if (j < 3 * 16384) {
            int which = j >> 14;
            int local = j & 16383;
            int k = local >> 7;
            int n = local & 127;
            const float* W = (which == 0) ? W1 : (which == 1) ? W2 : W3;
            _Float16* Wt = (which == 0) ? Wt1 : (which == 1) ? Wt2 : Wt3;
            Wt[(size_t)n * DIM + k] = (_Float16)W[local];
        }
    }
}

// ---------------------------------------------------------------- aggregation (R10 form)
// One wave per node, paired edges (lanes 0-31: even, 32-63: odd). Single clamped
// 16-edge round: 8 gathers in flight per lane, indices clamped to e1-1 (legal),
// accumulation predicated on e < e1. No branch between index load and gather.
__global__ __launch_bounds__(256) void k_agg(const uint2* __restrict__ A,
                                             const int* __restrict__ row_ptr,
                                             const int* __restrict__ csr,
                                             const float* __restrict__ nd,
                                             uint2* __restrict__ Bh, int N) {
    int gtid = blockIdx.x * blockDim.x + threadIdx.x;
    int node = gtid >> 6;
    int lane = threadIdx.x & 63;
    if (node >= N) return;
    int e0 = row_ptr[node];
    int e1 = row_ptr[node + 1];
    int half = lane >> 5;    // 0: even edge, 1: odd edge
    int l8 = lane & 31;      // 8-byte slot within 256B row
    float ax = 0.f, ay = 0.f, az = 0.f, aw = 0.f;

    for (int base = e0; base < e1; base += 16) {
        int idx[8];
        uint2 u[8];
#pragma unroll
        for (int j = 0; j < 8; ++j) {
            int ee = base + 2 * j + half;
            idx[j] = csr[min(ee, e1 - 1)];
        }
#pragma unroll
        for (int j = 0; j < 8; ++j) {
            u[j] = A[(size_t)idx[j] * 32 + l8];
        }
#pragma unroll
        for (int j = 0; j < 8; ++j) {
            int ee = base + 2 * j + half;
            if (ee < e1) {
                __half2 p0 = *(__half2*)&u[j].x;
                __half2 p1 = *(__half2*)&u[j].y;
                float2 f0 = __half22float2(p0);
                float2 f1 = __half22float2(p1);
                ax += f0.x; ay += f0.y; az += f1.x; aw += f1.y;
            }
        }
    }

    ax += __shfl_xor(ax, 32);
    ay += __shfl_xor(ay, 32);
    az += __shfl_xor(az, 32);
    aw += __shfl_xor(aw, 32);

    if (half == 0) {
        float scale = nd[node];
        __half2 p0 = __floats2half2_rn(ax * scale, ay * scale);
        __half2 p1 = __floats2half2_rn(az * scale, aw * scale);
        uint2 o;
        o.x = *(unsigned*)&p0;
        o.y = *(unsigned*)&p1;
        Bh[(size_t)node * 32 + l8] = o;
    }
}

// ---------------------------------------------------------------- GEMM on matrix cores
// X = relu(Bin @ W + b). Bin fp16 [N][128], Wt fp16 [n][k]. 4 waves x 16 rows = 64 rows/block.
// A: lane=A[m=l16][k=quad*8+j]; B: lane=B[k=quad*8+j][n=l16]; C/D: col=l16, row=quad*4+reg.
// Output fp16; SCALE_NS multiplies rows by ns (layers 1-2).
template <bool SCALE_NS>
__global__ __launch_bounds__(256) void k_gemm_mfma(
    const _Float16* __restrict__ Bin, const _Float16* __restrict__ Wt,
    const float* __restrict__ bias, const float* __restrict__ ns,
    _Float16* __restrict__ Xout, int N) {
    int tid = threadIdx.x;
    int wave = tid >> 6;
    int lane = tid & 63;
    int quad = lane >> 4;
    int l16 = lane & 15;
    int r0 = blockIdx.x * 64 + wave * 16;
    int arow = r0 + l16;

    half8 a[4];
#pragma unroll
    for (int q = 0; q < 4; ++q) {
        if (arow < N) {
            a[q] = *(const half8*)&Bin[(size_t)arow * DIM + q * 32 + quad * 8];
        } else {
            a[q] = half8{0, 0, 0, 0, 0, 0, 0, 0};
        }
    }

    floatx4 acc[8];
#pragma unroll
    for (int c = 0; c < 8; ++c) acc[c] = floatx4{0.f, 0.f, 0.f, 0.f};

#pragma unroll
    for (int c = 0; c < 8; ++c) {
#pragma unroll
        for (int q = 0; q < 4; ++q) {
            half8 b = *(const half8*)&Wt[(size_t)(c * 16 + l16) * DIM + q * 32 + quad * 8];
            acc[c] = __builtin_amdgcn_mfma_f32_16x16x32_f16(a[q], b, acc[c], 0, 0, 0);
        }
    }

    float bb[8];
#pragma unroll
    for (int c = 0; c < 8; ++c) bb[c] = bias[c * 16 + l16];

#pragma unroll
    for (int r = 0; r < 4; ++r) {
        int row = r0 + quad * 4 + r;
        if (row >= N) continue;
        float sr = SCALE_NS ? ns[row] : 1.0f;
#pragma unroll
        for (int c = 0; c < 8; ++c) {
            float v = fmaxf(acc[c][r] + bb[c], 0.0f);
            Xout[(size_t)row * DIM + c * 16 + l16] = (_Float16)(v * sr);
        }
    }
}

// ---------------------------------------------------------------- pooling (fp16 input)
#define POOL_NODES 32
__global__ void k_pool_partial(const _Float16* __restrict__ X, const int* __restrict__ gid,
                               float* __restrict__ gsum, int* __restrict__ gcnt, int N) {
    int n0 = blockIdx.x * POOL_NODES;
    int d = threadIdx.x;  // 0..127
    int nend = min(n0 + POOL_NODES, N);
    float run = 0.0f;
    int cnt = 0;
    int curg = -1;
    for (int n = n0; n < nend; ++n) {
        int g = gid[n];
        if (g != curg) {
            if (cnt > 0) {
                atomicAdd(&gsum[curg * DIM + d], run);
                if (d == 0) atomicAdd(&gcnt[curg], cnt);
            }
            run = 0.0f; cnt = 0; curg = g;
        }
        run += (float)X[(size_t)n * DIM + d];
        cnt++;
    }
    if (cnt > 0) {
        atomicAdd(&gsum[curg * DIM + d], run);
        if (d == 0) atomicAdd(&gcnt[curg], cnt);
    }
}

__global__ void k_finalize(const float* __restrict__ gsum, const int* __restrict__ gcnt,
                           float* __restrict__ out, int G) {
    int i = blockIdx.x * blockDim.x + threadIdx.x;
    if (i < G * DIM) {
        int g = i >> 7;
        float c = fmaxf((float)gcnt[g], 1.0f);
        out[i] = gsum[i] / c;
    }
}

// ---------------------------------------------------------------- launch
extern "C" void kernel_launch(void* const* d_in, const int* in_sizes, int n_in,
                              void* d_out, int out_size, void* d_ws, size_t ws_size,
                              hipStream_t stream) {
    const float* h   = (const float*)d_in[0];
    const int*   src = (const int*)d_in[1];
    const int*   dst = (const int*)d_in[2];
    const int*   gid = (const int*)d_in[3];
    const float* W1  = (const float*)d_in[4];
    const float* b1  = (const float*)d_in[5];
    const float* W2  = (const float*)d_in[6];
    const float* b2  = (const float*)d_in[7];
    const float* W3  = (const float*)d_in[8];
    const float* b3  = (const float*)d_in[9];

    const int N = in_sizes[0] / DIM;   // 50000
    const int E = in_sizes[1];         // 600000
    const int G = GRAPHS;
    float* out = (float*)d_out;

    char* ws = (char*)d_ws;
    size_t off = 0;
    auto alloc = [&](size_t bytes) -> void* {
        void* p = ws + off;
        off += (bytes + 255) & ~(size_t)255;
        return p;
    };
    const int nb = (N + 255) / 256;    // 196
    uint2* Ah0     = (uint2*)alloc((size_t)N * DIM * 2);  // fp16 gather operand (ping)
    uint2* Ah1     = (uint2*)alloc((size_t)N * DIM * 2);  // fp16 pong
    uint2* Bh      = (uint2*)alloc((size_t)N * DIM * 2);  // agg output (fp16)
    _Float16* X3   = (_Float16*)alloc((size_t)N * DIM * 2);  // layer-3 fp16 output
    _Float16* Wt1  = (_Float16*)alloc((size_t)DIM * DIM * 2);
    _Float16* Wt2  = (_Float16*)alloc((size_t)DIM * DIM * 2);
    _Float16* Wt3  = (_Float16*)alloc((size_t)DIM * DIM * 2);
    float* ns      = (float*)alloc((size_t)N * 4);
    float* nd      = (float*)alloc((size_t)N * 4);
    int*   inc     = (int*)alloc((size_t)N * 4);
    unsigned* partial = (unsigned*)alloc((size_t)2 * HIST_R * HIST_S * LDSW * 4);  // 12.8 MB
    int*   cur     = (int*)alloc((size_t)HIST_R * HIST_S * NPR * 4);               // 12.8 MB
    int*   row_ptr = (int*)alloc((size_t)(N + 1) * 4);
    int*   csr     = (int*)alloc((size_t)E * 4);
    float* gsum    = (float*)alloc((size_t)G * DIM * 4);
    int*   gcnt    = (int*)alloc((size_t)G * 4);
    int*   bsum    = (int*)alloc((size_t)nb * 4);

    // degrees via LDS histograms (no global atomics)
    k_hist<<<2 * HIST_R * HIST_S, 256, 0, stream>>>(src, dst, partial, E);
    // merge -> ns/nd/inc + per-block sums
    k_hist_merge<<<2 * nb, 256, 0, stream>>>(partial, ns, nd, inc, bsum, N);
    // row_ptr + per-(range,slice) cursors + gsum/gcnt zero (scan_top + cursor folded in)
    k_scan_write<<<nb, 256, 0, stream>>>(inc, bsum, partial, row_ptr, cur, gsum, gcnt, N);
    k_fill2<<<HIST_R * HIST_S, 256, 0, stream>>>(src, dst, cur, csr, E);

    // Ah0 = fp16(h*ns) + weights -> fp16 transposed (single launch)
    int prepThreads = N * 32 + 3 * 16384;
    k_prep<<<(prepThreads + 255) / 256, 256, 0, stream>>>((const float4*)h, ns, Ah0,
                                                          W1, W2, W3, Wt1, Wt2, Wt3, N);

    int aggBlocks  = (N * 64 + 255) / 256;
    int gemmBlocks = (N + 63) / 64;

    // layer 1
    k_agg<<<aggBlocks, 256, 0, stream>>>(Ah0, row_ptr, csr, nd, Bh, N);
    k_gemm_mfma<true><<<gemmBlocks, 256, 0, stream>>>((const _Float16*)Bh, Wt1, b1, ns, (_Float16*)Ah1, N);
    // layer 2
    k_agg<<<aggBlocks, 256, 0, stream>>>(Ah1, row_ptr, csr, nd, Bh, N);
    k_gemm_mfma<true><<<gemmBlocks, 256, 0, stream>>>((const _Float16*)Bh, Wt2, b2, ns, (_Float16*)Ah0, N);
    // layer 3 (fp16 out, no ns)
    k_agg<<<aggBlocks, 256, 0, stream>>>(Ah0, row_ptr, csr, nd, Bh, N);
    k_gemm_mfma<false><<<gemmBlocks, 256, 0, stream>>>((const _Float16*)Bh, Wt3, b3, ns, X3, N);

    k_pool_partial<<<(N + POOL_NODES - 1) / POOL_NODES, 128, 0, stream>>>(X3, gid, gsum, gcnt, N);
    k_finalize<<<(G * DIM + 255) / 256, 256, 0, stream>>>(gsum, gcnt, out, G);
}